// Round 1
// baseline (185.709 us; speedup 1.0000x reference)
//
#include <hip/hip_runtime.h>

#define IMG    384
#define IMG2   (IMG*IMG)
#define CROP   378
#define BORD   3
#define NBATCH 64
#define SROWS  14            // rows per stripe
#define SPB    3             // stripes per block
#define NGRP   9             // 9 groups * 3 stripes * 14 rows = 378
#define NI     7
#define NVAL   43            // 6 sums * 7 j + Sp
#define NVPAD  44
#define CROW   95            // 4-px chunks per row (covers 378 with 2-px tail)
#define NCHUNK (SROWS*CROW)  // 1330
#define NF4    (SROWS*(IMG/4)) // 1344 float4 per stripe
#define LDSF   (SROWS*IMG + 16)

__device__ __forceinline__ float wave_sum_f(float v) {
    v += __shfl_down(v, 32);
    v += __shfl_down(v, 16);
    v += __shfl_down(v, 8);
    v += __shfl_down(v, 4);
    v += __shfl_down(v, 2);
    v += __shfl_down(v, 1);
    return v;
}

__global__ __launch_bounds__(256)
void corr_kernel(const float* __restrict__ sr, const float* __restrict__ hr,
                 const float* __restrict__ mk, float* __restrict__ part)
{
    __shared__ float lq[LDSF];
    __shared__ float lm[LDSF];

    const int tid = threadIdx.x;
    const int grp = blockIdx.x;   // 0..8
    const int ii  = blockIdx.y;   // 0..6  (row shift i)
    const int b   = blockIdx.z;   // 0..63

    const float* sb = sr + (size_t)b * IMG2;
    const float* hb = hr + (size_t)b * IMG2;
    const float* mb = mk + (size_t)b * IMG2;

    float aA[7]  = {0,0,0,0,0,0,0};
    float aB[7]  = {0,0,0,0,0,0,0};
    float aC[7]  = {0,0,0,0,0,0,0};
    float aN[7]  = {0,0,0,0,0,0,0};
    float aSq[7] = {0,0,0,0,0,0,0};
    float aQ2[7] = {0,0,0,0,0,0,0};
    float aSp = 0.f;

    for (int ss = 0; ss < SPB; ++ss) {
        const int r0 = (grp * SPB + ss) * SROWS;  // crop-row start of stripe
        const int g0 = r0 + ii;                   // image-row start of shifted window

        if (ss) __syncthreads();                  // protect prev-iter LDS reads

        // ---- stage stripe: q = hr*mask and mask, full 384-wide rows ----
        const float4* h4p = (const float4*)(hb + (size_t)g0 * IMG);
        const float4* m4p = (const float4*)(mb + (size_t)g0 * IMG);
        float4* q4d = (float4*)lq;
        float4* m4d = (float4*)lm;
        for (int t = tid; t < NF4; t += 256) {
            float4 h4 = h4p[t];
            float4 m4 = m4p[t];
            float4 q4 = make_float4(h4.x*m4.x, h4.y*m4.y, h4.z*m4.z, h4.w*m4.w);
            q4d[t] = q4;
            m4d[t] = m4;
        }
        if (ss == 0 && tid < 16) {   // zero over-read pad: avoid 0*NaN poisoning
            lq[SROWS*IMG + tid] = 0.f;
            lm[SROWS*IMG + tid] = 0.f;
        }
        __syncthreads();

        // ---- accumulate ----
        const float4* q4l = (const float4*)lq;
        const float4* m4l = (const float4*)lm;
        for (int c = tid; c < NCHUNK; c += 256) {
            const int y  = c / CROW;
            const int xc = c - y * CROW;
            const int x4 = xc * 4;
            const int f4 = y * (IMG/4) + xc;

            float4 q0 = q4l[f4], q1 = q4l[f4+1], q2 = q4l[f4+2];
            float4 m0 = m4l[f4], m1 = m4l[f4+1], m2 = m4l[f4+2];
            float qe[12], me[12];
            qe[0]=q0.x; qe[1]=q0.y; qe[2]=q0.z;  qe[3]=q0.w;
            qe[4]=q1.x; qe[5]=q1.y; qe[6]=q1.z;  qe[7]=q1.w;
            qe[8]=q2.x; qe[9]=q2.y; qe[10]=q2.z; qe[11]=q2.w;
            me[0]=m0.x; me[1]=m0.y; me[2]=m0.z;  me[3]=m0.w;
            me[4]=m1.x; me[5]=m1.y; me[6]=m1.z;  me[7]=m1.w;
            me[8]=m2.x; me[9]=m2.y; me[10]=m2.z; me[11]=m2.w;

            const size_t po = (size_t)(r0 + y + BORD) * IMG + (x4 + BORD);
            float pk[4];
            #pragma unroll
            for (int k = 0; k < 4; ++k) pk[k] = sb[po + k] * mb[po + k];
            if (xc == CROW - 1) { pk[2] = 0.f; pk[3] = 0.f; }  // px 378,379 invalid

            #pragma unroll
            for (int k = 0; k < 4; ++k) {
                const float p = pk[k], p2 = p * p;
                #pragma unroll
                for (int j = 0; j < 7; ++j) {
                    aA[j] = fmaf(p,  qe[k+j], aA[j]);
                    aB[j] = fmaf(p2, me[k+j], aB[j]);
                    aC[j] = fmaf(p,  me[k+j], aC[j]);
                }
                aSp += p;
            }
            if (xc < CROW - 1) {
                #pragma unroll
                for (int k = 0; k < 4; ++k)
                    #pragma unroll
                    for (int j = 0; j < 7; ++j) {
                        aN[j]  += me[k+j];
                        aSq[j] += qe[k+j];
                        aQ2[j]  = fmaf(qe[k+j], qe[k+j], aQ2[j]);
                    }
            } else {
                #pragma unroll
                for (int k = 0; k < 2; ++k)
                    #pragma unroll
                    for (int j = 0; j < 7; ++j) {
                        aN[j]  += me[k+j];
                        aSq[j] += qe[k+j];
                        aQ2[j]  = fmaf(qe[k+j], qe[k+j], aQ2[j]);
                    }
            }
        }
    }
    __syncthreads();

    // ---- block reduction: wave butterflies -> LDS -> partials ----
    float* wbuf = lq;                 // reuse LDS; need 4*NVPAD floats
    const int wv = tid >> 6, ln = tid & 63;
    #pragma unroll
    for (int j = 0; j < 7; ++j) {
        float v;
        v = wave_sum_f(aA[j]);  if (ln == 0) wbuf[wv*NVPAD +      j] = v;
        v = wave_sum_f(aB[j]);  if (ln == 0) wbuf[wv*NVPAD +  7 + j] = v;
        v = wave_sum_f(aC[j]);  if (ln == 0) wbuf[wv*NVPAD + 14 + j] = v;
        v = wave_sum_f(aN[j]);  if (ln == 0) wbuf[wv*NVPAD + 21 + j] = v;
        v = wave_sum_f(aSq[j]); if (ln == 0) wbuf[wv*NVPAD + 28 + j] = v;
        v = wave_sum_f(aQ2[j]); if (ln == 0) wbuf[wv*NVPAD + 35 + j] = v;
    }
    { float v = wave_sum_f(aSp); if (ln == 0) wbuf[wv*NVPAD + 42] = v; }
    __syncthreads();

    if (tid < NVAL) {
        float s = wbuf[tid] + wbuf[NVPAD + tid] + wbuf[2*NVPAD + tid] + wbuf[3*NVPAD + tid];
        part[(((size_t)b * NI + ii) * NGRP + grp) * NVPAD + tid] = s;
    }
}

__global__ __launch_bounds__(64)
void mse_kernel(const float* __restrict__ part, double* __restrict__ bmin)
{
    const int b = blockIdx.x;
    const int s = threadIdx.x;            // 0..63, shifts 0..48 active
    double mse = 1e300;
    if (s < 49) {
        const int i = s / 7, j = s % 7;
        double A=0, B=0, C=0, N=0, Sq=0, Q2=0, Sp=0;
        for (int g = 0; g < NGRP; ++g) {
            const float* p = part + (((size_t)b * NI + i) * NGRP + g) * NVPAD;
            A  += p[     j];
            B  += p[ 7 + j];
            C  += p[14 + j];
            N  += p[21 + j];
            Sq += p[28 + j];
            Q2 += p[35 + j];
            Sp += p[42];
        }
        const double bs = (Sq - Sp) / N;
        mse = (Q2 - 2.0*A - 2.0*bs*Sq + B + 2.0*bs*C + bs*bs*N) / N;
    }
    for (int off = 32; off; off >>= 1) {
        double o = __shfl_down(mse, off);
        mse = fmin(mse, o);
    }
    if (s == 0) bmin[b] = mse;
}

__global__ __launch_bounds__(64)
void mean_kernel(const double* __restrict__ bmin, float* __restrict__ out)
{
    double v = bmin[threadIdx.x];
    for (int off = 32; off; off >>= 1) v += __shfl_down(v, off);
    if (threadIdx.x == 0) out[0] = (float)(v / 64.0);
}

extern "C" void kernel_launch(void* const* d_in, const int* in_sizes, int n_in,
                              void* d_out, int out_size, void* d_ws, size_t ws_size,
                              hipStream_t stream) {
    const float* sr = (const float*)d_in[0];
    const float* hr = (const float*)d_in[1];
    const float* mk = (const float*)d_in[2];

    float*  part = (float*)d_ws;
    const size_t part_bytes = (size_t)NBATCH * NI * NGRP * NVPAD * sizeof(float); // 709632
    double* bmin = (double*)((char*)d_ws + part_bytes);

    dim3 grid(NGRP, NI, NBATCH);
    corr_kernel<<<grid, 256, 0, stream>>>(sr, hr, mk, part);
    mse_kernel<<<dim3(NBATCH), 64, 0, stream>>>(part, bmin);
    mean_kernel<<<dim3(1), 64, 0, stream>>>(bmin, (float*)d_out);
}